// Round 1
// baseline (326.284 us; speedup 1.0000x reference)
//
#include <hip/hip_runtime.h>

// Problem constants (fixed by reference setup_inputs):
//   K=4 slots, H=512, B=4 branching, T=1024 trees, D=3 levels, N0=65536 leaves.
// Algebraic collapse: out = P3@(M.T)^3 + 16c@(M.T)^2 + 4c@M.T + c
//   M = Wzf @ (sum_k Wz[k]),  c = 4*((sum_k bz[k]) @ Wzf.T + bzf)
//   P3[t] = sum of x over the 64 contiguous leaves of tree t.

#define HD    512
#define NTREE 1024

// ---------------- Kernel 1: Wsum = sum_k Wz[k]  (float4 elementwise) -------
__global__ __launch_bounds__(256) void wsum_kernel(const float* __restrict__ Wz,
                                                   float* __restrict__ Wsum) {
    int i = blockIdx.x * 256 + threadIdx.x;          // 0 .. 65535 (float4 units)
    const float4* w = (const float4*)Wz;
    float4 a = w[i];
    float4 b = w[i + 65536];
    float4 c = w[i + 131072];
    float4 d = w[i + 196608];
    float4 o;
    o.x = a.x + b.x + c.x + d.x;
    o.y = a.y + b.y + c.y + d.y;
    o.z = a.z + b.z + c.z + d.z;
    o.w = a.w + b.w + c.w + d.w;
    ((float4*)Wsum)[i] = o;
}

// ---------------- Kernel 2: c0[j] = 4*(dot(bsum, Wzf[j,:]) + bzf[j]) -------
__global__ __launch_bounds__(64) void c0_kernel(const float* __restrict__ bz,
                                                const float* __restrict__ Wzf,
                                                const float* __restrict__ bzf,
                                                float* __restrict__ c0) {
    int j = blockIdx.x;          // 0..511
    int lane = threadIdx.x;      // 0..63
    float p = 0.f;
    #pragma unroll
    for (int h = lane; h < HD; h += 64) {
        float bs = bz[h] + bz[HD + h] + bz[2 * HD + h] + bz[3 * HD + h];
        p += bs * Wzf[j * HD + h];
    }
    #pragma unroll
    for (int off = 32; off > 0; off >>= 1) p += __shfl_down(p, off);
    if (lane == 0) c0[j] = 4.f * (p + bzf[j]);
}

// ---------------- Kernel 3: P3[t][h] = sum over 64 leaves ------------------
// x: [65536, 512] fp32 row-major.  One thread per (tree, float4-column).
__global__ __launch_bounds__(256) void pool64_kernel(const float* __restrict__ x,
                                                     float* __restrict__ P3) {
    int gid  = blockIdx.x * 256 + threadIdx.x;  // 0 .. 131071
    int tree = gid >> 7;                        // /128
    int col4 = gid & 127;
    const float4* xp = (const float4*)x + (size_t)tree * 64 * 128 + col4;
    float4 acc = make_float4(0.f, 0.f, 0.f, 0.f);
    #pragma unroll 8
    for (int r = 0; r < 64; ++r) {
        float4 v = xp[(size_t)r * 128];
        acc.x += v.x; acc.y += v.y; acc.z += v.z; acc.w += v.w;
    }
    ((float4*)P3)[gid] = acc;
}

// ---------------- Kernel 4: tiled fp32 GEMM --------------------------------
// C[i,j] = sum_h A[i,h] * (TRANSB ? B[j,h] : B[h,j])  + bscale * bias[j]
// A: [Mdim,512] row-major. N==K==512. 64x64 C-tile, 4x4 microtile, KT=16.
// LDS layout As[kk][row] / Bs[kk][col], row stride 68 floats (16B-aligned,
// <=2-way bank aliasing which is free on CDNA4).
template <bool TRANSB>
__global__ __launch_bounds__(256)
void gemm_kernel(const float* __restrict__ A, const float* __restrict__ B,
                 float* __restrict__ C, const float* __restrict__ bias,
                 float bscale) {
    constexpr int LDT = 68;
    __shared__ float As[16][LDT];
    __shared__ float Bs[16][LDT];

    const int tid = threadIdx.x;
    const int tx = tid & 15;          // 0..15 -> C column group
    const int ty = tid >> 4;          // 0..15 -> C row group
    const int i0 = blockIdx.y << 6;
    const int j0 = blockIdx.x << 6;

    const int srow = tid >> 2;        // 0..63  staging row/col
    const int sc4  = (tid & 3) << 2;  // 0,4,8,12 staging k-offset

    float acc[4][4] = {};

    for (int k0 = 0; k0 < 512; k0 += 16) {
        __syncthreads();
        { // A tile -> As[kk][row] (transposed scatter, ~2-way banks: free)
            float4 v = *(const float4*)&A[(size_t)(i0 + srow) * HD + k0 + sc4];
            As[sc4 + 0][srow] = v.x; As[sc4 + 1][srow] = v.y;
            As[sc4 + 2][srow] = v.z; As[sc4 + 3][srow] = v.w;
        }
        if (TRANSB) { // B[j,h]: same pattern as A
            float4 v = *(const float4*)&B[(size_t)(j0 + srow) * HD + k0 + sc4];
            Bs[sc4 + 0][srow] = v.x; Bs[sc4 + 1][srow] = v.y;
            Bs[sc4 + 2][srow] = v.z; Bs[sc4 + 3][srow] = v.w;
        } else {      // B[h,j]: direct coalesced copy
            int col = tid & 63, kq = (tid >> 6) << 2;
            #pragma unroll
            for (int i = 0; i < 4; ++i)
                Bs[kq + i][col] = B[(size_t)(k0 + kq + i) * HD + j0 + col];
        }
        __syncthreads();

        #pragma unroll
        for (int kk = 0; kk < 16; ++kk) {
            float4 av = *(const float4*)&As[kk][ty << 2]; // 4 rows, broadcast
            float4 bv = *(const float4*)&Bs[kk][tx << 2]; // 4 cols
            float aa[4] = {av.x, av.y, av.z, av.w};
            float bb[4] = {bv.x, bv.y, bv.z, bv.w};
            #pragma unroll
            for (int i = 0; i < 4; ++i)
                #pragma unroll
                for (int j = 0; j < 4; ++j)
                    acc[i][j] += aa[i] * bb[j];
        }
    }

    // Epilogue: fused bias (wave-uniform branch on bias != nullptr)
    float4 bv = make_float4(0.f, 0.f, 0.f, 0.f);
    if (bias) {
        float4 t = *(const float4*)&bias[j0 + (tx << 2)];
        bv.x = bscale * t.x; bv.y = bscale * t.y;
        bv.z = bscale * t.z; bv.w = bscale * t.w;
    }
    #pragma unroll
    for (int i = 0; i < 4; ++i) {
        int row = i0 + (ty << 2) + i;
        float4 o;
        o.x = acc[i][0] + bv.x;
        o.y = acc[i][1] + bv.y;
        o.z = acc[i][2] + bv.z;
        o.w = acc[i][3] + bv.w;
        *(float4*)&C[(size_t)row * HD + j0 + (tx << 2)] = o;
    }
}

extern "C" void kernel_launch(void* const* d_in, const int* in_sizes, int n_in,
                              void* d_out, int out_size, void* d_ws, size_t ws_size,
                              hipStream_t stream) {
    const float* x   = (const float*)d_in[0];
    const float* Wz  = (const float*)d_in[1];
    const float* bz  = (const float*)d_in[2];
    const float* Wzf = (const float*)d_in[3];
    const float* bzf = (const float*)d_in[4];
    float* out = (float*)d_out;

    float* ws   = (float*)d_ws;
    float* wsA  = ws;               // 524288 floats: P3, later Y2
    float* wsB  = ws + 524288;      // 524288 floats: Y1
    float* Wsum = ws + 1048576;     // 262144 floats
    float* Mmat = ws + 1310720;     // 262144 floats
    float* c0   = ws + 1572864;     // 512 floats   (total ~6.0 MiB)

    // Precompute Wsum, c0, P3 (independent)
    hipLaunchKernelGGL(wsum_kernel, dim3(256), dim3(256), 0, stream, Wz, Wsum);
    hipLaunchKernelGGL(c0_kernel,   dim3(512), dim3(64),  0, stream, bz, Wzf, bzf, c0);
    hipLaunchKernelGGL(pool64_kernel, dim3(512), dim3(256), 0, stream, x, wsA);

    // M = Wzf @ Wsum   (NN, 512x512x512)
    hipLaunchKernelGGL((gemm_kernel<false>), dim3(8, 8), dim3(256), 0, stream,
                       Wzf, Wsum, Mmat, (const float*)nullptr, 0.f);

    // out = ((P3@M.T + 16c)@M.T + 4c)@M.T + c   (three NT GEMMs, 1024x512x512)
    hipLaunchKernelGGL((gemm_kernel<true>), dim3(8, 16), dim3(256), 0, stream,
                       wsA, Mmat, wsB, c0, 16.f);
    hipLaunchKernelGGL((gemm_kernel<true>), dim3(8, 16), dim3(256), 0, stream,
                       wsB, Mmat, wsA, c0, 4.f);
    hipLaunchKernelGGL((gemm_kernel<true>), dim3(8, 16), dim3(256), 0, stream,
                       wsA, Mmat, out, c0, 1.f);
}

// Round 2
// 309.083 us; speedup vs baseline: 1.0556x; 1.0556x over previous
//
#include <hip/hip_runtime.h>

// Problem constants: K=4 slots, H=512, B=4, T=1024 trees, D=3 levels, N0=65536.
// Collapse: out = P3@(M.T)^3 + 16c@(M.T)^2 + 4c@M.T + c
// Re-associated: out = Y1 @ (M^2).T + u
//   M  = Wzf @ Wsum,  Wsum = sum_k Wz[k]   (fused into B-staging of M-GEMM)
//   c  = 4*((sum_k bz[k]) @ Wzf.T + bzf)
//   Y1 = P3 @ M.T + 16c
//   u  = 4c @ M.T + c
//   P3[t] = sum of x over the 64 contiguous leaves of tree t.
// 3 dispatches: D1={pool, M, c}, D2={M2, Y1, u}, D3={out}.

#define HD 512
#define LDA_T 34   // As row stride (floats): float2 reads 8B-aligned, 2-way banks (free)
#define LDB_T 68   // Bs row stride (floats): float4 reads 16B-aligned, 2-way banks (free)

struct GemmSmem {
    float As[2][32][LDA_T];
    float Bs[2][32][LDB_T];
};

// Tiled SGEMM: C[i0:i0+32, j0:j0+64] = A @ op(B) + bscale*bias
// MODE 0: B[h,j] (NN)   MODE 1: NN where B = Wz, summed over 4 slices (Wsum fusion)
// MODE 2: B[j,h] (NT)
// 256 threads, KT=32, double-buffered LDS, ONE barrier per k-tile:
//   store at iter t targets buf[(t+1)&1]; its previous readers (compute t-1)
//   are fenced by the barrier ending iter t-1; visibility for compute t+1 is
//   fenced by the barrier ending iter t.
template<int MODE>
__device__ __forceinline__
void gemm_tile(const float* __restrict__ A, const float* __restrict__ B,
               float* __restrict__ C, const float* __restrict__ bias,
               float bscale, int i0, int j0, GemmSmem& sm) {
    const int tid  = threadIdx.x;
    const int tx   = tid & 15, ty = tid >> 4;          // 2x4 microtile coords
    const int arow = tid >> 3, acol4 = (tid & 7) << 2; // A staging
    const int ntcol = tid & 63, ntkq = (tid >> 6) << 3; // NT B staging
    const int nncol4 = (tid & 15) << 2, nnk = tid >> 4; // NN B staging

    float4 apre, bpre0, bpre1;

    auto load_tiles = [&](int k0) {
        apre = *(const float4*)&A[(size_t)(i0 + arow) * HD + k0 + acol4];
        if (MODE == 2) {
            const float* bp = &B[(size_t)(j0 + ntcol) * HD + k0 + ntkq];
            bpre0 = *(const float4*)bp;
            bpre1 = *(const float4*)(bp + 4);
        } else if (MODE == 0) {
            bpre0 = *(const float4*)&B[(size_t)(k0 + nnk) * HD + j0 + nncol4];
            bpre1 = *(const float4*)&B[(size_t)(k0 + nnk + 16) * HD + j0 + nncol4];
        } else {
            const float* b0 = &B[(size_t)(k0 + nnk) * HD + j0 + nncol4];
            const float* b1 = &B[(size_t)(k0 + nnk + 16) * HD + j0 + nncol4];
            float4 s0 = *(const float4*)b0, s1 = *(const float4*)b1;
            #pragma unroll
            for (int q = 1; q < 4; ++q) {
                float4 t0 = *(const float4*)(b0 + q * 262144);
                float4 t1 = *(const float4*)(b1 + q * 262144);
                s0.x += t0.x; s0.y += t0.y; s0.z += t0.z; s0.w += t0.w;
                s1.x += t1.x; s1.y += t1.y; s1.z += t1.z; s1.w += t1.w;
            }
            bpre0 = s0; bpre1 = s1;
        }
    };
    auto store_tiles = [&](int buf) {
        sm.As[buf][acol4 + 0][arow] = apre.x;
        sm.As[buf][acol4 + 1][arow] = apre.y;
        sm.As[buf][acol4 + 2][arow] = apre.z;
        sm.As[buf][acol4 + 3][arow] = apre.w;
        if (MODE == 2) {
            sm.Bs[buf][ntkq + 0][ntcol] = bpre0.x;
            sm.Bs[buf][ntkq + 1][ntcol] = bpre0.y;
            sm.Bs[buf][ntkq + 2][ntcol] = bpre0.z;
            sm.Bs[buf][ntkq + 3][ntcol] = bpre0.w;
            sm.Bs[buf][ntkq + 4][ntcol] = bpre1.x;
            sm.Bs[buf][ntkq + 5][ntcol] = bpre1.y;
            sm.Bs[buf][ntkq + 6][ntcol] = bpre1.z;
            sm.Bs[buf][ntkq + 7][ntcol] = bpre1.w;
        } else {
            *(float4*)&sm.Bs[buf][nnk][nncol4]      = bpre0;
            *(float4*)&sm.Bs[buf][nnk + 16][nncol4] = bpre1;
        }
    };

    float acc[2][4] = {};

    load_tiles(0);
    store_tiles(0);
    __syncthreads();

    for (int t = 0; t < 16; ++t) {
        if (t < 15) load_tiles((t + 1) << 5);  // global prefetch, max latency slack
        const int cur = t & 1;
        #pragma unroll
        for (int kk = 0; kk < 32; ++kk) {
            float2 av = *(const float2*)&sm.As[cur][kk][ty << 1];
            float4 bv = *(const float4*)&sm.Bs[cur][kk][tx << 2];
            acc[0][0] += av.x * bv.x; acc[0][1] += av.x * bv.y;
            acc[0][2] += av.x * bv.z; acc[0][3] += av.x * bv.w;
            acc[1][0] += av.y * bv.x; acc[1][1] += av.y * bv.y;
            acc[1][2] += av.y * bv.z; acc[1][3] += av.y * bv.w;
        }
        if (t < 15) {
            store_tiles(1 - cur);
            __syncthreads();
        }
    }

    float4 bv = make_float4(0.f, 0.f, 0.f, 0.f);
    if (bias) {
        float4 tb = *(const float4*)&bias[j0 + (tx << 2)];
        bv.x = bscale * tb.x; bv.y = bscale * tb.y;
        bv.z = bscale * tb.z; bv.w = bscale * tb.w;
    }
    #pragma unroll
    for (int r = 0; r < 2; ++r) {
        const int row = i0 + (ty << 1) + r;
        float4 o;
        o.x = acc[r][0] + bv.x; o.y = acc[r][1] + bv.y;
        o.z = acc[r][2] + bv.z; o.w = acc[r][3] + bv.w;
        *(float4*)&C[(size_t)row * HD + j0 + (tx << 2)] = o;
    }
}

// ---- D1: blocks [0,512) pool x->P3 | [512,640) M = Wzf@Wsum | 640: c0 ----
__global__ __launch_bounds__(256) void k_stage1(
        const float* __restrict__ x, const float* __restrict__ Wz,
        const float* __restrict__ Wzf, const float* __restrict__ bz,
        const float* __restrict__ bzf,
        float* __restrict__ P3, float* __restrict__ M, float* __restrict__ c0) {
    __shared__ GemmSmem sm;
    const int b = blockIdx.x, tid = threadIdx.x;
    if (b < 512) {
        const int gid  = (b << 8) + tid;
        const int tree = gid >> 7, col4 = gid & 127;
        const float4* xp = (const float4*)x + (size_t)tree * 8192 + col4;
        float4 a0 = make_float4(0,0,0,0), a1 = a0, a2 = a0, a3 = a0;
        #pragma unroll 4
        for (int r = 0; r < 64; r += 4) {
            float4 v0 = xp[(size_t)(r + 0) * 128];
            float4 v1 = xp[(size_t)(r + 1) * 128];
            float4 v2 = xp[(size_t)(r + 2) * 128];
            float4 v3 = xp[(size_t)(r + 3) * 128];
            a0.x += v0.x; a0.y += v0.y; a0.z += v0.z; a0.w += v0.w;
            a1.x += v1.x; a1.y += v1.y; a1.z += v1.z; a1.w += v1.w;
            a2.x += v2.x; a2.y += v2.y; a2.z += v2.z; a2.w += v2.w;
            a3.x += v3.x; a3.y += v3.y; a3.z += v3.z; a3.w += v3.w;
        }
        float4 o;
        o.x = (a0.x + a1.x) + (a2.x + a3.x);
        o.y = (a0.y + a1.y) + (a2.y + a3.y);
        o.z = (a0.z + a1.z) + (a2.z + a3.z);
        o.w = (a0.w + a1.w) + (a2.w + a3.w);
        ((float4*)P3)[gid] = o;
    } else if (b < 640) {
        const int bb = b - 512;
        gemm_tile<1>(Wzf, Wz, M, nullptr, 0.f, (bb >> 3) << 5, (bb & 7) << 6, sm);
    } else {
        float* bs = (float*)&sm;  // 512-float scratch for bsum
        if (tid < 128) {
            const int h = tid << 2;
            #pragma unroll
            for (int i = 0; i < 4; ++i)
                bs[h + i] = bz[h + i] + bz[512 + h + i] + bz[1024 + h + i] + bz[1536 + h + i];
        }
        __syncthreads();
        #pragma unroll
        for (int r = 0; r < 2; ++r) {
            const int j = tid + (r << 8);
            float s = 0.f;
            for (int h = 0; h < HD; h += 4) {
                float4 w = *(const float4*)&Wzf[(size_t)j * HD + h];
                s += w.x * bs[h] + w.y * bs[h + 1] + w.z * bs[h + 2] + w.w * bs[h + 3];
            }
            c0[j] = 4.f * (s + bzf[j]);
        }
    }
}

// ---- D2: [0,128) M2 = M@M | [128,384) Y1 = P3@M.T + 16c | [384,386) u ----
__global__ __launch_bounds__(256) void k_stage2(
        const float* __restrict__ M, const float* __restrict__ P3,
        const float* __restrict__ c0,
        float* __restrict__ M2, float* __restrict__ Y1, float* __restrict__ u) {
    __shared__ GemmSmem sm;
    const int b = blockIdx.x;
    if (b < 128) {
        gemm_tile<0>(M, M, M2, nullptr, 0.f, (b >> 3) << 5, (b & 7) << 6, sm);
    } else if (b < 384) {
        const int bb = b - 128;
        gemm_tile<2>(P3, M, Y1, c0, 16.f, (bb >> 3) << 5, (bb & 7) << 6, sm);
    } else {
        const int j = ((b - 384) << 8) + threadIdx.x;  // 0..511
        float s = 0.f;
        for (int h = 0; h < HD; h += 4) {
            float4 m = *(const float4*)&M[(size_t)j * HD + h];
            float4 c = *(const float4*)&c0[h];
            s += m.x * c.x + m.y * c.y + m.z * c.z + m.w * c.w;
        }
        u[j] = 4.f * s + c0[j];
    }
}

// ---- D3: out = Y1 @ (M2).T + u  (256 blocks) ----
__global__ __launch_bounds__(256) void k_stage3(
        const float* __restrict__ Y1, const float* __restrict__ M2,
        const float* __restrict__ u, float* __restrict__ out) {
    __shared__ GemmSmem sm;
    const int b = blockIdx.x;
    gemm_tile<2>(Y1, M2, out, u, 1.f, (b >> 3) << 5, (b & 7) << 6, sm);
}

extern "C" void kernel_launch(void* const* d_in, const int* in_sizes, int n_in,
                              void* d_out, int out_size, void* d_ws, size_t ws_size,
                              hipStream_t stream) {
    const float* x   = (const float*)d_in[0];
    const float* Wz  = (const float*)d_in[1];
    const float* bz  = (const float*)d_in[2];
    const float* Wzf = (const float*)d_in[3];
    const float* bzf = (const float*)d_in[4];
    float* out = (float*)d_out;

    float* ws = (float*)d_ws;
    float* P3 = ws;                 // 1024*512
    float* Y1 = ws + 524288;        // 1024*512
    float* M  = ws + 1048576;       // 512*512
    float* M2 = ws + 1310720;       // 512*512
    float* c0 = ws + 1572864;       // 512
    float* u  = ws + 1573376;       // 512

    hipLaunchKernelGGL(k_stage1, dim3(641), dim3(256), 0, stream,
                       x, Wz, Wzf, bz, bzf, P3, M, c0);
    hipLaunchKernelGGL(k_stage2, dim3(386), dim3(256), 0, stream,
                       M, P3, c0, M2, Y1, u);
    hipLaunchKernelGGL(k_stage3, dim3(256), dim3(256), 0, stream,
                       Y1, M2, u, out);
}